// Round 2
// baseline (105.305 us; speedup 1.0000x reference)
//
#include <hip/hip_runtime.h>

#define DEV __device__ __forceinline__

namespace {

struct CF { float x, y; };

DEV CF cmul(CF a, float c, float s){ return {a.x*c - a.y*s, a.x*s + a.y*c}; }
DEV void halfsc(float th, float& c, float& s){ __sincosf(0.5f*th, &s, &c); }

constexpr float RSQRT2 = 0.70710678118654752440f;
constexpr float PI_F   = 3.14159265358979323846f;

// ---------- cross-lane xor exchange: masks 1,2 via DPP quad_perm (VALU pipe),
// ---------- masks 4,8 via ds_swizzle (LDS pipe, no index VALU) --------------
template<int CTRL> DEV float qperm(float v){
  return __int_as_float(__builtin_amdgcn_mov_dpp(__float_as_int(v), CTRL, 0xF, 0xF, true));
}
template<int OFF> DEV float swzf(float v){
  return __int_as_float(__builtin_amdgcn_ds_swizzle(__float_as_int(v), OFF));
}
template<int B> DEV float shfx(float v){
  if constexpr (B==1)      return qperm<0xB1>(v);      // [1,0,3,2]
  else if constexpr (B==2) return qperm<0x4E>(v);      // [2,3,0,1]
  else if constexpr (B==4) return swzf<0x101F>(v);     // xor 4, BitMode
  else                     return swzf<0x201F>(v);     // xor 8
}

// ---------------- local gates on a 16-amp register state, target mask S ----
template<int S> DEV void h_loc(CF (&a)[16]){
  #pragma unroll
  for (int m = 0; m < 16; ++m) if (!(m & S)) {
    CF u = a[m], v = a[m|S];
    a[m]   = {(u.x+v.x)*RSQRT2, (u.y+v.y)*RSQRT2};
    a[m|S] = {(u.x-v.x)*RSQRT2, (u.y-v.y)*RSQRT2};
  }
}
template<int S> DEV void rz_loc(CF (&a)[16], float th){
  float c, s; halfsc(th, c, s);
  #pragma unroll
  for (int m = 0; m < 16; ++m){
    float se = (m & S) ? s : -s;
    a[m] = cmul(a[m], c, se);
  }
}
template<int S> DEV void rx_loc(CF (&a)[16], float th){
  float c, s; halfsc(th, c, s);
  #pragma unroll
  for (int m = 0; m < 16; ++m) if (!(m & S)) {
    CF u = a[m], v = a[m|S];
    a[m]   = {c*u.x + s*v.y, c*u.y - s*v.x};
    a[m|S] = {c*v.x + s*u.y, c*v.y - s*u.x};
  }
}
template<int S> DEV void ry_loc(CF (&a)[16], float th){
  float c, s; halfsc(th, c, s);
  #pragma unroll
  for (int m = 0; m < 16; ++m) if (!(m & S)) {
    CF u = a[m], v = a[m|S];
    a[m]   = {c*u.x - s*v.x, c*u.y - s*v.y};
    a[m|S] = {s*u.x + c*v.x, s*u.y + c*v.y};
  }
}
template<int SC,int ST> DEV void crz_loc(CF (&a)[16], float th){
  float c, s; halfsc(th, c, s);
  #pragma unroll
  for (int m = 0; m < 16; ++m) if (m & SC) {
    float se = (m & ST) ? s : -s;
    a[m] = cmul(a[m], c, se);
  }
}

// ---------------- 16x16 register transpose across the 16-lane group --------
// element (r, m) -> (m, r); 4 butterfly steps; ONE float-pair shuffle per reg-pair.
template<int B> DEV void tstep(CF (&a)[16], int r){
  const bool hi = (r & B) != 0;
  #pragma unroll
  for (int m0 = 0; m0 < 16; ++m0) if (!(m0 & B)) {
    const int m1 = m0 | B;
    float sx = hi ? a[m0].x : a[m1].x;
    float sy = hi ? a[m0].y : a[m1].y;
    float wx = shfx<B>(sx);
    float wy = shfx<B>(sy);
    a[m0].x = hi ? wx : a[m0].x;  a[m0].y = hi ? wy : a[m0].y;
    a[m1].x = hi ? a[m1].x : wx;  a[m1].y = hi ? a[m1].y : wy;
  }
}
DEV void transpose16(CF (&a)[16], int r){
  tstep<1>(a, r); tstep<2>(a, r); tstep<4>(a, r); tstep<8>(a, r);
}

// ---------------- circuit8 pieces -------------------------------------------
// Layout L2: lane bits = wires 0-3 (wire w <-> r-bit 3-w); local = wires 4-7
//           (wire 4+k <-> m-bit 3-k).
// Layout L1: the transpose of L2 (local = wires 0-3, lanes = wires 4-7).
template<int W,int LAY> struct WB {
  static constexpr bool lane = (LAY==2) ? (W < 4) : (W >= 4);
  static constexpr int  mask = (W < 4) ? (8 >> W) : (8 >> (W-4));
};
template<int CW,int TW,int LAY> DEV void crzg(CF (&a)[16], int r, float th){
  float c, s; halfsc(th, c, s);
  constexpr bool CL = WB<CW,LAY>::lane; constexpr int CM = WB<CW,LAY>::mask;
  constexpr bool TL = WB<TW,LAY>::lane; constexpr int TM = WB<TW,LAY>::mask;
  const bool cbl = CL && ((r & CM) != 0);
  const bool tbl = TL && ((r & TM) != 0);
  #pragma unroll
  for (int m = 0; m < 16; ++m){
    const bool cb = CL ? cbl : ((m & CM) != 0);
    const bool tb = TL ? tbl : ((m & TM) != 0);
    float cc = cb ? c : 1.0f;
    float ss = cb ? (tb ? s : -s) : 0.0f;
    a[m] = cmul(a[m], cc, ss);
  }
}
template<int LAY> DEV void layer_crz(CF (&a)[16], int r, const float* wl){
  crzg<0,1,LAY>(a,r,wl[0]); crzg<1,2,LAY>(a,r,wl[1]);
  crzg<2,3,LAY>(a,r,wl[2]); crzg<3,4,LAY>(a,r,wl[3]);
  crzg<4,5,LAY>(a,r,wl[4]); crzg<5,6,LAY>(a,r,wl[5]);
  crzg<6,7,LAY>(a,r,wl[6]); crzg<7,0,LAY>(a,r,wl[7]);
}
DEV void ry4pack(CF (&a)[16], const float* wl){   // 4 local RYs, masks 8,4,2,1
  ry_loc<8>(a, wl[0]); ry_loc<4>(a, wl[1]); ry_loc<2>(a, wl[2]); ry_loc<1>(a, wl[3]);
}
// encoding of wires 0-3 (all idx < 36 valid) on a local 16-amp state
template<int Q> DEV void encw03(CF (&a)[16], const float* f){
  constexpr int S = 8 >> Q;
  h_loc<S>(a);
  #pragma unroll
  for (int i = 0; i < 9; ++i){
    float th = PI_F * f[Q*9 + i];
    if ((i & 1) == 0) rz_loc<S>(a, th);
    else              rx_loc<S>(a, th);
  }
}
// encoding of wire 4+K on local state (L2), idx bound 64 folds at compile time
template<int K> DEV void encw47(CF (&a)[16], const float* f){
  constexpr int S = 8 >> K;
  h_loc<S>(a);
  #pragma unroll
  for (int i = 0; i < 9; ++i){
    const int idx = (4+K)*9 + i;
    if (idx < 64){
      float th = PI_F * f[idx];
      if ((i & 1) == 0) rz_loc<S>(a, th);
      else              rx_loc<S>(a, th);
    }
  }
}

} // namespace

__global__ __launch_bounds__(512)
void qnn_fused_kernel(const float* __restrict__ X,  const float* __restrict__ w1,
                      const float* __restrict__ w2, const float* __restrict__ fcw,
                      const float* __restrict__ fcb, float* __restrict__ out, int bs)
{
  __shared__ float feats[32][65];           // +1 pad: conflict-free group reads
  const int t  = threadIdx.x;
  const int sl = t >> 4;                    // local sample 0..31
  const int r  = t & 15;                    // role: patch id (ph1) / lane-bits (ph2)
  int sample = blockIdx.x * 32 + sl;
  if (sample >= bs) sample = bs - 1;        // duplicate work, uniform barriers

  // ---------------- phase 1: one 4-qubit circuit (patch r) per thread ------
  {
    const int pi = r >> 2, pj = r & 3;
    const int i0 = pi*4, j0 = pj*4;
    const float* xs = X + (size_t)sample * 196;
    float px[16];
    #pragma unroll
    for (int k = 0; k < 16; ++k) px[k] = 0.f;  // pad: RZ(0)/RX(0) == identity
    if (pi < 3 && pj < 3) {
      #pragma unroll
      for (int rr = 0; rr < 4; ++rr)
        #pragma unroll
        for (int cc = 0; cc < 4; ++cc)
          px[rr*4+cc] = xs[(i0+rr)*14 + j0 + cc];
    } else if (pi == 3 && pj < 3) {
      #pragma unroll
      for (int rr = 0; rr < 2; ++rr)
        #pragma unroll
        for (int cc = 0; cc < 4; ++cc)
          px[rr*4+cc] = xs[(12+rr)*14 + j0 + cc];
    } else if (pi < 3) {
      #pragma unroll
      for (int rr = 0; rr < 4; ++rr)
        #pragma unroll
        for (int cc = 0; cc < 2; ++cc)
          px[rr*2+cc] = xs[(i0+rr)*14 + 12 + cc];
    } else {
      #pragma unroll
      for (int rr = 0; rr < 2; ++rr)
        #pragma unroll
        for (int cc = 0; cc < 2; ++cc)
          px[rr*2+cc] = xs[(12+rr)*14 + 12 + cc];
    }

    CF a[16];
    #pragma unroll
    for (int m = 0; m < 16; ++m) a[m] = {0.f, 0.f};
    a[0] = {1.f, 0.f};
    // encoding: wire q: H, then RZ/RX alternating with px[q*4+i]
    h_loc<8>(a); rz_loc<8>(a,px[0]);  rx_loc<8>(a,px[1]);  rz_loc<8>(a,px[2]);  rx_loc<8>(a,px[3]);
    h_loc<4>(a); rz_loc<4>(a,px[4]);  rx_loc<4>(a,px[5]);  rz_loc<4>(a,px[6]);  rx_loc<4>(a,px[7]);
    h_loc<2>(a); rz_loc<2>(a,px[8]);  rx_loc<2>(a,px[9]);  rz_loc<2>(a,px[10]); rx_loc<2>(a,px[11]);
    h_loc<1>(a); rz_loc<1>(a,px[12]); rx_loc<1>(a,px[13]); rz_loc<1>(a,px[14]); rx_loc<1>(a,px[15]);
    #pragma unroll
    for (int l = 0; l < 2; ++l){
      const float* wl = w1 + l*8;
      crz_loc<8,4>(a, wl[0]); crz_loc<4,2>(a, wl[1]);
      crz_loc<2,1>(a, wl[2]); crz_loc<1,8>(a, wl[3]);
      ry_loc<8>(a, wl[4]); ry_loc<4>(a, wl[5]); ry_loc<2>(a, wl[6]); ry_loc<1>(a, wl[7]);
    }
    float pr[16];
    #pragma unroll
    for (int m = 0; m < 16; ++m) pr[m] = a[m].x*a[m].x + a[m].y*a[m].y;
    #pragma unroll
    for (int w = 0; w < 4; ++w){
      const int S = 8 >> w;
      float e = 0.f;
      #pragma unroll
      for (int m = 0; m < 16; ++m) e += (m & S) ? -pr[m] : pr[m];
      feats[sl][r*4 + w] = e;
    }
  }
  __syncthreads();

  // ---------------- phase 2: 8-qubit circuit, 16 lanes cooperate -----------
  const float* f = feats[sl];

  // wires 0-3 act on a product state: every lane computes psi4 (f is uniform
  // across the 16-lane group; compile-time zeros let the compiler DCE the
  // sparse early gates), then scatters a[0] = psi4[r]  (state enters L2).
  CF p4[16];
  #pragma unroll
  for (int m = 0; m < 16; ++m) p4[m] = {0.f, 0.f};
  p4[0] = {1.f, 0.f};
  encw03<0>(p4, f); encw03<1>(p4, f); encw03<2>(p4, f); encw03<3>(p4, f);

  CF a[16];
  #pragma unroll
  for (int m = 0; m < 16; ++m) a[m] = {0.f, 0.f};
  {  // a[0] = p4[r] via cndmask tree (no runtime register indexing)
    const bool b3 = (r & 8) != 0, b2 = (r & 4) != 0, b1 = (r & 2) != 0, b0 = (r & 1) != 0;
    CF s8[8], s4[4], s2[2];
    #pragma unroll
    for (int m = 0; m < 8; ++m){ s8[m].x = b3 ? p4[m+8].x : p4[m].x;
                                 s8[m].y = b3 ? p4[m+8].y : p4[m].y; }
    #pragma unroll
    for (int m = 0; m < 4; ++m){ s4[m].x = b2 ? s8[m+4].x : s8[m].x;
                                 s4[m].y = b2 ? s8[m+4].y : s8[m].y; }
    #pragma unroll
    for (int m = 0; m < 2; ++m){ s2[m].x = b1 ? s4[m+2].x : s4[m].x;
                                 s2[m].y = b1 ? s4[m+2].y : s4[m].y; }
    a[0].x = b0 ? s2[1].x : s2[0].x;
    a[0].y = b0 ? s2[1].y : s2[0].y;
  }

  // wires 4-7 encoding, local in L2 (starts from single nonzero amp -> DCE)
  encw47<0>(a, f); encw47<1>(a, f); encw47<2>(a, f); encw47<3>(a, f);

  // layer 0 (L2): CRZ; RY 4-7 local; transpose -> L1; RY 0-3 local
  layer_crz<2>(a, r, w2 + 0);
  ry4pack(a, w2 + 12);
  transpose16(a, r);
  ry4pack(a, w2 + 8);
  // layer 1 (L1): CRZ; RY 0-3 local; transpose -> L2; RY 4-7 local
  layer_crz<1>(a, r, w2 + 16);
  ry4pack(a, w2 + 16 + 8);
  transpose16(a, r);
  ry4pack(a, w2 + 16 + 12);
  // layer 2 (L2): CRZ; RY 4-7 local; transpose -> L1; RY 0-3 local
  layer_crz<2>(a, r, w2 + 32);
  ry4pack(a, w2 + 32 + 12);
  transpose16(a, r);
  ry4pack(a, w2 + 32 + 8);

  // ---------------- measurement in L1: local = wires 0-3, lanes = wires 4-7
  float pr[16];
  #pragma unroll
  for (int m = 0; m < 16; ++m) pr[m] = a[m].x*a[m].x + a[m].y*a[m].y;
  float Ssum = 0.f;
  #pragma unroll
  for (int m = 0; m < 16; ++m) Ssum += pr[m];
  float gp[8];
  #pragma unroll
  for (int w = 0; w < 4; ++w){
    const int S = 8 >> w;
    float e = 0.f;
    #pragma unroll
    for (int m = 0; m < 16; ++m) e += (m & S) ? -pr[m] : pr[m];
    gp[w] = e;
  }
  gp[4] = (r & 8) ? -Ssum : Ssum;
  gp[5] = (r & 4) ? -Ssum : Ssum;
  gp[6] = (r & 2) ? -Ssum : Ssum;
  gp[7] = (r & 1) ? -Ssum : Ssum;

  // FC partials per lane, then one 3-value all-reduce over the 16-lane group
  float o0 = 0.f, o1 = 0.f, o2 = 0.f;
  #pragma unroll
  for (int w = 0; w < 8; ++w){
    o0 += fcw[0*8 + w] * gp[w];
    o1 += fcw[1*8 + w] * gp[w];
    o2 += fcw[2*8 + w] * gp[w];
  }
  o0 += shfx<1>(o0); o1 += shfx<1>(o1); o2 += shfx<1>(o2);
  o0 += shfx<2>(o0); o1 += shfx<2>(o1); o2 += shfx<2>(o2);
  o0 += shfx<4>(o0); o1 += shfx<4>(o1); o2 += shfx<4>(o2);
  o0 += shfx<8>(o0); o1 += shfx<8>(o1); o2 += shfx<8>(o2);

  if (r < 3){
    float o = (r == 0) ? o0 : ((r == 1) ? o1 : o2);
    out[(size_t)sample*3 + r] = o + fcb[r];
  }
}

extern "C" void kernel_launch(void* const* d_in, const int* in_sizes, int n_in,
                              void* d_out, int out_size, void* d_ws, size_t ws_size,
                              hipStream_t stream)
{
  const float* X   = (const float*)d_in[0];
  const float* w1  = (const float*)d_in[1];
  const float* w2  = (const float*)d_in[2];
  const float* fcw = (const float*)d_in[3];
  const float* fcb = (const float*)d_in[4];
  float* out = (float*)d_out;
  const int bs = in_sizes[0] / 196;            // 8192
  const int blocks = (bs + 31) / 32;           // 32 samples / block
  hipLaunchKernelGGL(qnn_fused_kernel, dim3(blocks), dim3(512), 0, stream,
                     X, w1, w2, fcw, fcb, out, bs);
}

// Round 3
// 26.793 us; speedup vs baseline: 3.9304x; 3.9304x over previous
//
#include <hip/hip_runtime.h>

#define DEV __device__ __forceinline__

namespace {

struct CF { float x, y; };

DEV CF cmul(CF a, float c, float s){ return {a.x*c - a.y*s, a.x*s + a.y*c}; }
DEV CF cmulc(CF a, CF b){ return {a.x*b.x - a.y*b.y, a.x*b.y + a.y*b.x}; }
DEV void halfsc(float th, float& c, float& s){ __sincosf(0.5f*th, &s, &c); }

constexpr float RSQRT2 = 0.70710678118654752440f;
constexpr float PI_F   = 3.14159265358979323846f;

// ---------- cross-lane xor exchange: masks 1,2 via DPP quad_perm (VALU pipe),
// ---------- masks 4,8 via ds_swizzle (LDS pipe) — verified in round 2 -------
template<int CTRL> DEV float qperm(float v){
  return __int_as_float(__builtin_amdgcn_mov_dpp(__float_as_int(v), CTRL, 0xF, 0xF, true));
}
template<int OFF> DEV float swzf(float v){
  return __int_as_float(__builtin_amdgcn_ds_swizzle(__float_as_int(v), OFF));
}
template<int B> DEV float shfx(float v){
  if constexpr (B==1)      return qperm<0xB1>(v);      // [1,0,3,2]
  else if constexpr (B==2) return qperm<0x4E>(v);      // [2,3,0,1]
  else if constexpr (B==4) return swzf<0x101F>(v);     // xor 4, BitMode
  else                     return swzf<0x201F>(v);     // xor 8
}

// ---------- fused 1-qubit encoding chain: H; then RZ/RX alternating --------
// returns first column of the product (the encoded 1-qubit state)
template<int NA> DEV void build_psi(CF (&v)[2], const float* ang, float scale){
  v[0] = {RSQRT2, 0.f};
  v[1] = {RSQRT2, 0.f};
  #pragma unroll
  for (int i = 0; i < NA; ++i){
    float c, s; halfsc(scale * ang[i], c, s);
    if ((i & 1) == 0){                     // RZ: diag(e^{-it/2}, e^{+it/2})
      v[0] = cmul(v[0], c, -s);
      v[1] = cmul(v[1], c,  s);
    } else {                               // RX: [[c,-is],[-is,c]]
      CF u0 = v[0], u1 = v[1];
      v[0] = {c*u0.x + s*u1.y, c*u0.y - s*u1.x};
      v[1] = {c*u1.x + s*u0.y, c*u1.y - s*u0.x};
    }
  }
}

// ---------------- local gates on a 16-amp register state -------------------
template<int S> DEV void ry_loc(CF (&a)[16], float th){
  float c, s; halfsc(th, c, s);
  #pragma unroll
  for (int m = 0; m < 16; ++m) if (!(m & S)) {
    CF u = a[m], v = a[m|S];
    a[m]   = {c*u.x - s*v.x, c*u.y - s*v.y};
    a[m|S] = {s*u.x + c*v.x, s*u.y + c*v.y};
  }
}
template<int SC,int ST> DEV void crz_loc(CF (&a)[16], float th){
  float c, s; halfsc(th, c, s);
  #pragma unroll
  for (int m = 0; m < 16; ++m) if (m & SC) {
    float se = (m & ST) ? s : -s;
    a[m] = cmul(a[m], c, se);
  }
}
// RY on a lane wire (mask over the 16-lane group id r)
template<int MASK> DEV void ry_lane(CF (&a)[16], int r, float th){
  float c, s; halfsc(th, c, s);
  float sg = (r & MASK) ? s : -s;
  #pragma unroll
  for (int m = 0; m < 16; ++m){
    float ox = shfx<MASK>(a[m].x);
    float oy = shfx<MASK>(a[m].y);
    a[m] = {c*a[m].x + sg*ox, c*a[m].y + sg*oy};
  }
}

// ---------- merged CRZ ring (8 diagonal gates -> 1 phase per amp) ----------
// layout: lane bits = wires 0-3 (wire w <-> r-bit 3-w); local = wires 4-7.
DEV void layer_crz_merged(CF (&a)[16], int r, const float* wl){
  float h0 = 0.5f*wl[0], h1 = 0.5f*wl[1], h2 = 0.5f*wl[2], h3 = 0.5f*wl[3];
  float h4 = 0.5f*wl[4], h5 = 0.5f*wl[5], h6 = 0.5f*wl[6], h7 = 0.5f*wl[7];
  const bool r8 = (r & 8), r4 = (r & 4), r2 = (r & 2), r1 = (r & 1);
  // lane-only gates: (w0,w1),(w1,w2),(w2,w3)
  float lanesum = 0.f;
  lanesum += r8 ? (r4 ? h0 : -h0) : 0.f;
  lanesum += r4 ? (r2 ? h1 : -h1) : 0.f;
  lanesum += r2 ? (r1 ? h2 : -h2) : 0.f;
  float t3 = r1 ? h3 : 0.f;          // (w3,w4): ctrl lane, tgt m&8
  float s7 = r8 ? h7 : -h7;          // (w7,w0): ctrl m&1, tgt lane sign
  #pragma unroll
  for (int m = 0; m < 16; ++m){
    float phi = lanesum;
    phi += (m & 8) ? t3 : -t3;
    if (m & 8) phi += (m & 4) ? h4 : -h4;   // (w4,w5)
    if (m & 4) phi += (m & 2) ? h5 : -h5;   // (w5,w6)
    if (m & 2) phi += (m & 1) ? h6 : -h6;   // (w6,w7)
    if (m & 1) phi += s7;                   // (w7,w0)
    float c, s; __sincosf(phi, &s, &c);     // e^{i phi}
    a[m] = cmul(a[m], c, s);
  }
}

DEV CF selc(const CF (&p)[2], bool b){ return { b ? p[1].x : p[0].x, b ? p[1].y : p[0].y }; }

} // namespace

__global__ __launch_bounds__(512)
void qnn_fused_kernel(const float* __restrict__ X,  const float* __restrict__ w1,
                      const float* __restrict__ w2, const float* __restrict__ fcw,
                      const float* __restrict__ fcb, float* __restrict__ out, int bs)
{
  __shared__ float feats[32][65];           // +1 pad: conflict-free group reads
  const int t  = threadIdx.x;
  const int sl = t >> 4;                    // local sample 0..31
  const int r  = t & 15;                    // role: patch id (ph1) / lane bits (ph2)
  int sample = blockIdx.x * 32 + sl;
  if (sample >= bs) sample = bs - 1;        // duplicate work, uniform barriers

  // ---------------- phase 1: one 4-qubit circuit (patch r) per thread ------
  {
    const int pi = r >> 2, pj = r & 3;
    const int i0 = pi*4, j0 = pj*4;
    const float* xs = X + (size_t)sample * 196;
    float px[16];
    #pragma unroll
    for (int k = 0; k < 16; ++k) px[k] = 0.f;  // pad: RZ(0)/RX(0) == identity
    if (pi < 3 && pj < 3) {
      #pragma unroll
      for (int rr = 0; rr < 4; ++rr)
        #pragma unroll
        for (int cc = 0; cc < 4; ++cc)
          px[rr*4+cc] = xs[(i0+rr)*14 + j0 + cc];
    } else if (pi == 3 && pj < 3) {
      #pragma unroll
      for (int rr = 0; rr < 2; ++rr)
        #pragma unroll
        for (int cc = 0; cc < 4; ++cc)
          px[rr*4+cc] = xs[(12+rr)*14 + j0 + cc];
    } else if (pi < 3) {
      #pragma unroll
      for (int rr = 0; rr < 4; ++rr)
        #pragma unroll
        for (int cc = 0; cc < 2; ++cc)
          px[rr*2+cc] = xs[(i0+rr)*14 + 12 + cc];
    } else {
      #pragma unroll
      for (int rr = 0; rr < 2; ++rr)
        #pragma unroll
        for (int cc = 0; cc < 2; ++cc)
          px[rr*2+cc] = xs[(12+rr)*14 + 12 + cc];
    }

    // encoding = tensor product of 4 fused 1-qubit states
    CF ps[4][2];
    #pragma unroll
    for (int q = 0; q < 4; ++q) build_psi<4>(ps[q], &px[q*4], 1.0f);

    CF a[16];
    {
      CF T01[4], T23[4];
      #pragma unroll
      for (int j = 0; j < 4; ++j){
        T01[j] = cmulc(ps[0][j>>1], ps[1][j&1]);
        T23[j] = cmulc(ps[2][j>>1], ps[3][j&1]);
      }
      #pragma unroll
      for (int m = 0; m < 16; ++m) a[m] = cmulc(T01[m>>2], T23[m&3]);
    }

    #pragma unroll
    for (int l = 0; l < 2; ++l){
      const float* wl = w1 + l*8;
      crz_loc<8,4>(a, wl[0]); crz_loc<4,2>(a, wl[1]);
      crz_loc<2,1>(a, wl[2]); crz_loc<1,8>(a, wl[3]);
      ry_loc<8>(a, wl[4]); ry_loc<4>(a, wl[5]); ry_loc<2>(a, wl[6]); ry_loc<1>(a, wl[7]);
    }
    float pr[16];
    #pragma unroll
    for (int m = 0; m < 16; ++m) pr[m] = a[m].x*a[m].x + a[m].y*a[m].y;
    #pragma unroll
    for (int w = 0; w < 4; ++w){
      const int S = 8 >> w;
      float e = 0.f;
      #pragma unroll
      for (int m = 0; m < 16; ++m) e += (m & S) ? -pr[m] : pr[m];
      feats[sl][r*4 + w] = e;
    }
  }
  __syncthreads();

  // ---------------- phase 2: 8-qubit circuit, 16 lanes cooperate -----------
  const float* f = feats[sl];

  // full encoding is a product state: 8 fused 1-qubit states (group-uniform)
  CF a[16];
  {
    CF ps8[8][2];
    #pragma unroll
    for (int w = 0; w < 7; ++w) build_psi<9>(ps8[w], f + w*9, PI_F);
    build_psi<1>(ps8[7], f + 63, PI_F);     // wire 7: only idx 63 < 64

    // lane coefficient: wires 0-3 selected by r bits
    CF e0 = selc(ps8[0], r & 8);
    CF e1 = selc(ps8[1], r & 4);
    CF e2 = selc(ps8[2], r & 2);
    CF e3 = selc(ps8[3], r & 1);
    CF L  = cmulc(cmulc(e0, e1), cmulc(e2, e3));

    // local part: wires 4-7
    CF p45[4], p67[4];
    #pragma unroll
    for (int j = 0; j < 4; ++j){
      p45[j] = cmulc(ps8[4][j>>1], ps8[5][j&1]);
      p67[j] = cmulc(ps8[6][j>>1], ps8[7][j&1]);
    }
    CF Lp[4];
    #pragma unroll
    for (int j = 0; j < 4; ++j) Lp[j] = cmulc(L, p45[j]);
    #pragma unroll
    for (int m = 0; m < 16; ++m) a[m] = cmulc(Lp[m>>2], p67[m&3]);
  }

  // 3 layers: merged-CRZ ring, then RY on wires 0..7
  #pragma unroll
  for (int l = 0; l < 3; ++l){
    const float* wl = w2 + l*16;
    layer_crz_merged(a, r, wl);
    ry_lane<8>(a, r, wl[8]);  ry_lane<4>(a, r, wl[9]);
    ry_lane<2>(a, r, wl[10]); ry_lane<1>(a, r, wl[11]);
    ry_loc<8>(a, wl[12]); ry_loc<4>(a, wl[13]);
    ry_loc<2>(a, wl[14]); ry_loc<1>(a, wl[15]);
  }

  // ---------------- measurement (lanes = wires 0-3, local = wires 4-7) -----
  float pr[16];
  #pragma unroll
  for (int m = 0; m < 16; ++m) pr[m] = a[m].x*a[m].x + a[m].y*a[m].y;
  float Ssum = 0.f;
  #pragma unroll
  for (int m = 0; m < 16; ++m) Ssum += pr[m];
  float gp[8];
  gp[0] = (r & 8) ? -Ssum : Ssum;
  gp[1] = (r & 4) ? -Ssum : Ssum;
  gp[2] = (r & 2) ? -Ssum : Ssum;
  gp[3] = (r & 1) ? -Ssum : Ssum;
  #pragma unroll
  for (int w = 4; w < 8; ++w){
    const int S = 8 >> (w-4);
    float e = 0.f;
    #pragma unroll
    for (int m = 0; m < 16; ++m) e += (m & S) ? -pr[m] : pr[m];
    gp[w] = e;
  }

  // FC partials per lane, then one 3-value all-reduce over the 16-lane group
  float o0 = 0.f, o1 = 0.f, o2 = 0.f;
  #pragma unroll
  for (int w = 0; w < 8; ++w){
    o0 += fcw[0*8 + w] * gp[w];
    o1 += fcw[1*8 + w] * gp[w];
    o2 += fcw[2*8 + w] * gp[w];
  }
  o0 += shfx<1>(o0); o1 += shfx<1>(o1); o2 += shfx<1>(o2);
  o0 += shfx<2>(o0); o1 += shfx<2>(o1); o2 += shfx<2>(o2);
  o0 += shfx<4>(o0); o1 += shfx<4>(o1); o2 += shfx<4>(o2);
  o0 += shfx<8>(o0); o1 += shfx<8>(o1); o2 += shfx<8>(o2);

  if (r < 3){
    float o = (r == 0) ? o0 : ((r == 1) ? o1 : o2);
    out[(size_t)sample*3 + r] = o + fcb[r];
  }
}

extern "C" void kernel_launch(void* const* d_in, const int* in_sizes, int n_in,
                              void* d_out, int out_size, void* d_ws, size_t ws_size,
                              hipStream_t stream)
{
  const float* X   = (const float*)d_in[0];
  const float* w1  = (const float*)d_in[1];
  const float* w2  = (const float*)d_in[2];
  const float* fcw = (const float*)d_in[3];
  const float* fcb = (const float*)d_in[4];
  float* out = (float*)d_out;
  const int bs = in_sizes[0] / 196;            // 8192
  const int blocks = (bs + 31) / 32;           // 32 samples / block
  hipLaunchKernelGGL(qnn_fused_kernel, dim3(blocks), dim3(512), 0, stream,
                     X, w1, w2, fcw, fcb, out, bs);
}

// Round 4
// 21.999 us; speedup vs baseline: 4.7868x; 1.2179x over previous
//
#include <hip/hip_runtime.h>

#define DEV __device__ __forceinline__

namespace {

struct CF { float x, y; };

DEV CF cmul(CF a, float c, float s){ return {a.x*c - a.y*s, a.x*s + a.y*c}; }
DEV CF cmulc(CF a, CF b){ return {a.x*b.x - a.y*b.y, a.x*b.y + a.y*b.x}; }
DEV void halfsc(float th, float& c, float& s){ __sincosf(0.5f*th, &s, &c); }

constexpr float RSQRT2 = 0.70710678118654752440f;
constexpr float PI_F   = 3.14159265358979323846f;

// ---------- cross-lane xor exchange within an aligned 16-lane group --------
// masks 1,2: DPP quad_perm; mask 8: DPP row_ror:8 (ror by 8 in a 16-ring ==
// xor 8, self-inverse); mask 4: ds_swizzle (no DPP control for xor-4).
template<int CTRL> DEV float qperm(float v){
  return __int_as_float(__builtin_amdgcn_mov_dpp(__float_as_int(v), CTRL, 0xF, 0xF, true));
}
template<int OFF> DEV float swzf(float v){
  return __int_as_float(__builtin_amdgcn_ds_swizzle(__float_as_int(v), OFF));
}
template<int B> DEV float shfx(float v){
  if constexpr (B==1)      return qperm<0xB1>(v);      // quad_perm [1,0,3,2]
  else if constexpr (B==2) return qperm<0x4E>(v);      // quad_perm [2,3,0,1]
  else if constexpr (B==4) return swzf<0x101F>(v);     // BitMode xor 4
  else                     return qperm<0x128>(v);     // row_ror:8 == xor 8
}

// ---------- fused 1-qubit encoding chain: H; then RZ/RX alternating --------
template<int NA> DEV void build_psi(CF (&v)[2], const float* ang, float scale){
  v[0] = {RSQRT2, 0.f};
  v[1] = {RSQRT2, 0.f};
  #pragma unroll
  for (int i = 0; i < NA; ++i){
    float c, s; halfsc(scale * ang[i], c, s);
    if ((i & 1) == 0){                     // RZ: diag(e^{-it/2}, e^{+it/2})
      v[0] = cmul(v[0], c, -s);
      v[1] = cmul(v[1], c,  s);
    } else {                               // RX: [[c,-is],[-is,c]]
      CF u0 = v[0], u1 = v[1];
      v[0] = {c*u0.x + s*u1.y, c*u0.y - s*u1.x};
      v[1] = {c*u1.x + s*u0.y, c*u1.y - s*u0.x};
    }
  }
}

// ---------------- local gates, (c,s) precomputed (half-angle) --------------
template<int S> DEV void ry_loc(CF (&a)[16], float2 cs){
  const float c = cs.x, s = cs.y;
  #pragma unroll
  for (int m = 0; m < 16; ++m) if (!(m & S)) {
    CF u = a[m], v = a[m|S];
    a[m]   = {c*u.x - s*v.x, c*u.y - s*v.y};
    a[m|S] = {s*u.x + c*v.x, s*u.y + c*v.y};
  }
}
template<int SC,int ST> DEV void crz_loc(CF (&a)[16], float2 cs){
  const float c = cs.x, s = cs.y;
  #pragma unroll
  for (int m = 0; m < 16; ++m) if (m & SC) {
    float se = (m & ST) ? s : -s;
    a[m] = cmul(a[m], c, se);
  }
}
template<int MASK> DEV void ry_lane(CF (&a)[16], int r, float2 cs){
  const float c = cs.x;
  const float sg = (r & MASK) ? cs.y : -cs.y;
  #pragma unroll
  for (int m = 0; m < 16; ++m){
    float ox = shfx<MASK>(a[m].x);
    float oy = shfx<MASK>(a[m].y);
    a[m] = {c*a[m].x + sg*ox, c*a[m].y + sg*oy};
  }
}

DEV CF ld_cf(const float2 v){ return {v.x, v.y}; }

} // namespace

__global__ __launch_bounds__(256)
void qnn_fused_kernel(const float* __restrict__ X,  const float* __restrict__ w1,
                      const float* __restrict__ w2, const float* __restrict__ fcw,
                      const float* __restrict__ fcb, float* __restrict__ out, int bs)
{
  // 16 samples / 256-thread block
  __shared__ float  feats[16][80];          // [64..79] zero pad for chain 7
  __shared__ float4 chain_tab[16][9];       // 8 chains + bank pad
  __shared__ float2 p1w[16];                // phase-1 weight (c,s), half-angle
  __shared__ float2 ryw[24];                // phase-2 RY (c,s), half-angle
  __shared__ float2 phi_tab[3*16*17];       // merged-CRZ e^{i phi}, pad 17

  const int t  = threadIdx.x;
  const int sl = t >> 4;                    // local sample 0..15
  const int r  = t & 15;                    // role: patch id (ph1) / lane bits (ph2)
  int sample = blockIdx.x * 16 + sl;
  if (sample >= bs) sample = bs - 1;        // duplicate work, uniform barriers

  // ---------------- per-block weight tables (sample-independent) -----------
  if (t < 16){ float c, s; halfsc(w1[t], c, s); p1w[t] = {c, s}; }
  else if (t < 40){
    int idx = t - 16, l = idx >> 3, j = idx & 7;
    float c, s; halfsc(w2[l*16 + 8 + j], c, s); ryw[idx] = {c, s};
  }
  for (int idx = t; idx < 3*256; idx += 256){
    const int l = idx >> 8, rm = idx & 255, rr = rm >> 4, mm = rm & 15;
    const float* wl = w2 + l*16;
    const float h0 = 0.5f*wl[0], h1 = 0.5f*wl[1], h2 = 0.5f*wl[2], h3 = 0.5f*wl[3];
    const float h4 = 0.5f*wl[4], h5 = 0.5f*wl[5], h6 = 0.5f*wl[6], h7 = 0.5f*wl[7];
    const bool r8 = (rr & 8), r4 = (rr & 4), r2 = (rr & 2), r1 = (rr & 1);
    float phiv = 0.f;
    phiv += r8 ? (r4 ? h0 : -h0) : 0.f;     // CRZ(w0,w1)
    phiv += r4 ? (r2 ? h1 : -h1) : 0.f;     // CRZ(w1,w2)
    phiv += r2 ? (r1 ? h2 : -h2) : 0.f;     // CRZ(w2,w3)
    float t3 = r1 ? h3 : 0.f;               // CRZ(w3,w4)
    phiv += (mm & 8) ? t3 : -t3;
    if (mm & 8) phiv += (mm & 4) ? h4 : -h4; // CRZ(w4,w5)
    if (mm & 4) phiv += (mm & 2) ? h5 : -h5; // CRZ(w5,w6)
    if (mm & 2) phiv += (mm & 1) ? h6 : -h6; // CRZ(w6,w7)
    if (mm & 1) phiv += r8 ? h7 : -h7;       // CRZ(w7,w0)
    float cc, ss; __sincosf(phiv, &ss, &cc);
    phi_tab[(l*16 + rr)*17 + mm] = {cc, ss};
  }
  __syncthreads();

  // ---------------- phase 1: one 4-qubit circuit (patch r) per thread ------
  {
    const int pi = r >> 2, pj = r & 3;
    const int i0 = pi*4, j0 = pj*4;
    const float* xs = X + (size_t)sample * 196;
    float px[16];
    #pragma unroll
    for (int k = 0; k < 16; ++k) px[k] = 0.f;  // pad: RZ(0)/RX(0) == identity
    if (pi < 3 && pj < 3) {
      #pragma unroll
      for (int rr = 0; rr < 4; ++rr)
        #pragma unroll
        for (int cc = 0; cc < 4; ++cc)
          px[rr*4+cc] = xs[(i0+rr)*14 + j0 + cc];
    } else if (pi == 3 && pj < 3) {
      #pragma unroll
      for (int rr = 0; rr < 2; ++rr)
        #pragma unroll
        for (int cc = 0; cc < 4; ++cc)
          px[rr*4+cc] = xs[(12+rr)*14 + j0 + cc];
    } else if (pi < 3) {
      #pragma unroll
      for (int rr = 0; rr < 4; ++rr)
        #pragma unroll
        for (int cc = 0; cc < 2; ++cc)
          px[rr*2+cc] = xs[(i0+rr)*14 + 12 + cc];
    } else {
      #pragma unroll
      for (int rr = 0; rr < 2; ++rr)
        #pragma unroll
        for (int cc = 0; cc < 2; ++cc)
          px[rr*2+cc] = xs[(12+rr)*14 + 12 + cc];
    }

    // encoding = tensor product of 4 fused 1-qubit states
    CF ps[4][2];
    #pragma unroll
    for (int q = 0; q < 4; ++q) build_psi<4>(ps[q], &px[q*4], 1.0f);

    CF a[16];
    {
      CF T01[4], T23[4];
      #pragma unroll
      for (int j = 0; j < 4; ++j){
        T01[j] = cmulc(ps[0][j>>1], ps[1][j&1]);
        T23[j] = cmulc(ps[2][j>>1], ps[3][j&1]);
      }
      #pragma unroll
      for (int m = 0; m < 16; ++m) a[m] = cmulc(T01[m>>2], T23[m&3]);
    }

    #pragma unroll
    for (int l = 0; l < 2; ++l){
      crz_loc<8,4>(a, p1w[l*8+0]); crz_loc<4,2>(a, p1w[l*8+1]);
      crz_loc<2,1>(a, p1w[l*8+2]); crz_loc<1,8>(a, p1w[l*8+3]);
      ry_loc<8>(a, p1w[l*8+4]); ry_loc<4>(a, p1w[l*8+5]);
      ry_loc<2>(a, p1w[l*8+6]); ry_loc<1>(a, p1w[l*8+7]);
    }
    float pr[16];
    #pragma unroll
    for (int m = 0; m < 16; ++m) pr[m] = a[m].x*a[m].x + a[m].y*a[m].y;
    #pragma unroll
    for (int w = 0; w < 4; ++w){
      const int S = 8 >> w;
      float e = 0.f;
      #pragma unroll
      for (int m = 0; m < 16; ++m) e += (m & S) ? -pr[m] : pr[m];
      feats[sl][r*4 + w] = e;
    }
    feats[sl][64 + r] = 0.f;                 // zero pad f[64..79]
  }
  __syncthreads();

  // -------- phase 2 encoding chains: lane r builds chain r&7 (distributed) -
  {
    const float* f = feats[sl];
    CF v[2];
    const int c = r & 7;
    build_psi<9>(v, f + c*9, PI_F);          // chain 7: f[63] + zero-pad ids
    if (r < 8) chain_tab[sl][c] = {v[0].x, v[0].y, v[1].x, v[1].y};
  }
  __syncthreads();

  // ---------------- assemble product state (lanes=wires0-3, local=4-7) -----
  CF a[16];
  {
    const float2* c2 = (const float2*)&chain_tab[sl][0];  // [chain*2 + comp]
    CF e0 = ld_cf(c2[0*2 + ((r>>3)&1)]);
    CF e1 = ld_cf(c2[1*2 + ((r>>2)&1)]);
    CF e2 = ld_cf(c2[2*2 + ((r>>1)&1)]);
    CF e3 = ld_cf(c2[3*2 + ( r     &1)]);
    CF L  = cmulc(cmulc(e0, e1), cmulc(e2, e3));

    float4 q4 = chain_tab[sl][4], q5 = chain_tab[sl][5];
    float4 q6 = chain_tab[sl][6], q7 = chain_tab[sl][7];
    CF p4[2] = {{q4.x,q4.y},{q4.z,q4.w}};
    CF p5[2] = {{q5.x,q5.y},{q5.z,q5.w}};
    CF p6[2] = {{q6.x,q6.y},{q6.z,q6.w}};
    CF p7[2] = {{q7.x,q7.y},{q7.z,q7.w}};
    CF p45[4], p67[4];
    #pragma unroll
    for (int j = 0; j < 4; ++j){
      p45[j] = cmulc(p4[j>>1], p5[j&1]);
      p67[j] = cmulc(p6[j>>1], p7[j&1]);
    }
    CF Lp[4];
    #pragma unroll
    for (int j = 0; j < 4; ++j) Lp[j] = cmulc(L, p45[j]);
    #pragma unroll
    for (int m = 0; m < 16; ++m) a[m] = cmulc(Lp[m>>2], p67[m&3]);
  }

  // ---------------- 3 layers: table-CRZ ring + RY on wires 0..7 ------------
  #pragma unroll
  for (int l = 0; l < 3; ++l){
    const float2* ph = &phi_tab[(l*16 + r)*17];
    #pragma unroll
    for (int m = 0; m < 16; ++m){
      float2 cs = ph[m];
      a[m] = cmul(a[m], cs.x, cs.y);
    }
    ry_lane<8>(a, r, ryw[l*8+0]); ry_lane<4>(a, r, ryw[l*8+1]);
    ry_lane<2>(a, r, ryw[l*8+2]); ry_lane<1>(a, r, ryw[l*8+3]);
    ry_loc<8>(a, ryw[l*8+4]); ry_loc<4>(a, ryw[l*8+5]);
    ry_loc<2>(a, ryw[l*8+6]); ry_loc<1>(a, ryw[l*8+7]);
  }

  // ---------------- measurement (lanes = wires 0-3, local = wires 4-7) -----
  float pr[16];
  #pragma unroll
  for (int m = 0; m < 16; ++m) pr[m] = a[m].x*a[m].x + a[m].y*a[m].y;
  float Ssum = 0.f;
  #pragma unroll
  for (int m = 0; m < 16; ++m) Ssum += pr[m];
  float gp[8];
  gp[0] = (r & 8) ? -Ssum : Ssum;
  gp[1] = (r & 4) ? -Ssum : Ssum;
  gp[2] = (r & 2) ? -Ssum : Ssum;
  gp[3] = (r & 1) ? -Ssum : Ssum;
  #pragma unroll
  for (int w = 4; w < 8; ++w){
    const int S = 8 >> (w-4);
    float e = 0.f;
    #pragma unroll
    for (int m = 0; m < 16; ++m) e += (m & S) ? -pr[m] : pr[m];
    gp[w] = e;
  }

  // FC partials per lane, then one 3-value all-reduce over the 16-lane group
  float o0 = 0.f, o1 = 0.f, o2 = 0.f;
  #pragma unroll
  for (int w = 0; w < 8; ++w){
    o0 += fcw[0*8 + w] * gp[w];
    o1 += fcw[1*8 + w] * gp[w];
    o2 += fcw[2*8 + w] * gp[w];
  }
  o0 += shfx<1>(o0); o1 += shfx<1>(o1); o2 += shfx<1>(o2);
  o0 += shfx<2>(o0); o1 += shfx<2>(o1); o2 += shfx<2>(o2);
  o0 += shfx<4>(o0); o1 += shfx<4>(o1); o2 += shfx<4>(o2);
  o0 += shfx<8>(o0); o1 += shfx<8>(o1); o2 += shfx<8>(o2);

  if (r < 3){
    float o = (r == 0) ? o0 : ((r == 1) ? o1 : o2);
    out[(size_t)sample*3 + r] = o + fcb[r];
  }
}

extern "C" void kernel_launch(void* const* d_in, const int* in_sizes, int n_in,
                              void* d_out, int out_size, void* d_ws, size_t ws_size,
                              hipStream_t stream)
{
  const float* X   = (const float*)d_in[0];
  const float* w1  = (const float*)d_in[1];
  const float* w2  = (const float*)d_in[2];
  const float* fcw = (const float*)d_in[3];
  const float* fcb = (const float*)d_in[4];
  float* out = (float*)d_out;
  const int bs = in_sizes[0] / 196;            // 8192
  const int blocks = (bs + 15) / 16;           // 16 samples / 256-thread block
  hipLaunchKernelGGL(qnn_fused_kernel, dim3(blocks), dim3(256), 0, stream,
                     X, w1, w2, fcw, fcb, out, bs);
}